// Round 6
// baseline (197.420 us; speedup 1.0000x reference)
//
#include <hip/hip_runtime.h>

#define S_LEN 2048
#define E_DIM 1024
#define H_NUM 16
#define D_DIM 64

typedef unsigned short u16;
using bf16x8 = __attribute__((ext_vector_type(8))) short;   // 8 bf16 in 4 VGPRs
using f32x4  = __attribute__((ext_vector_type(4))) float;

#define MFMA16(A, B, C) __builtin_amdgcn_mfma_f32_16x16x32_bf16(A, B, C, 0, 0, 0)
#define QSCALE 0.18033688011112042f   // (1/sqrt(D)) * log2(e), folded into Q so attn uses exp2

__device__ __forceinline__ u16 f2bf(float f) {
    unsigned u = __float_as_uint(f);
    u += 0x7fffu + ((u >> 16) & 1u);            // RNE
    return (u16)(u >> 16);
}
__device__ __forceinline__ f32x4 fzero4() { f32x4 z; z[0]=0.f; z[1]=0.f; z[2]=0.f; z[3]=0.f; return z; }

// packed f32x2 -> bf16x2 (RNE)
__device__ __forceinline__ unsigned cvtpk(float a, float b) {
    unsigned r;
    asm("v_cvt_pk_bf16_f32 %0, %1, %2" : "=v"(r) : "v"(a), "v"(b));
    return r;
}
__device__ __forceinline__ float fexp2(float x) {
#if __has_builtin(__builtin_amdgcn_exp2f)
    return __builtin_amdgcn_exp2f(x);
#else
    float r; asm("v_exp_f32 %0, %1" : "=v"(r) : "v"(x)); return r;
#endif
}
__device__ __forceinline__ float frcp(float x) {
#if __has_builtin(__builtin_amdgcn_rcpf)
    return __builtin_amdgcn_rcpf(x);
#else
    float r; asm("v_rcp_f32 %0, %1" : "=v"(r) : "v"(x)); return r;
#endif
}

// async global->LDS, 16B per lane; LDS dest = wave-uniform base + lane*16
__device__ __forceinline__ void gll16(const u16* g, u16* l) {
    __builtin_amdgcn_global_load_lds(
        (const __attribute__((address_space(1))) void*)g,
        (__attribute__((address_space(3))) void*)l, 16, 0, 0);
}

// ---- swizzled 64x64 u16 tile staging via global_load_lds (both-sides XOR swizzle) ----
// LDS row r at bytes r*128; physical 16B slot s holds logical slot s^(r&7).
__device__ __forceinline__ void stage64(const u16* __restrict__ g, int gstride,
                                        u16* l, int wave, int lane) {
    #pragma unroll
    for (int i = 0; i < 2; i++) {
        const int r  = wave * 16 + i * 8 + (lane >> 3);
        const int sl = (lane & 7) ^ (r & 7);
        gll16(g + (size_t)r * gstride + sl * 8, l + (wave * 16 + i * 8) * 64);
    }
}
// read one bf16x8 fragment = logical u16 cols [(hh*4+quad)*8 .. +7] of row rr
__device__ __forceinline__ bf16x8 ldswz(const u16* t, int rr, int hh, int quad) {
    const int sl = ((hh << 2) + quad) ^ (rr & 7);
    return *(const bf16x8*)(t + rr * 64 + sl * 8);
}

// ---------------- fp32 [R,C] tile -> bf16 [C,R] transpose-convert helper ----------------
__device__ __forceinline__ void cvt_t_tile(const float* __restrict__ bin, u16* __restrict__ bout,
                                           int R, int C, int r0, int c0) {
    __shared__ float t[64][65];
    const int tid = threadIdx.x;
    const int lr = tid >> 2, lc = (tid & 3) * 16;

    const float* src = bin + (size_t)(r0 + lr) * C + c0 + lc;
    #pragma unroll
    for (int j = 0; j < 4; j++) {
        float4 f = *(const float4*)(src + j * 4);
        t[lr][lc + j * 4 + 0] = f.x; t[lr][lc + j * 4 + 1] = f.y;
        t[lr][lc + j * 4 + 2] = f.z; t[lr][lc + j * 4 + 3] = f.w;
    }
    __syncthreads();

    u16* dst = bout + (size_t)(c0 + lr) * R + r0 + lc;
    u16 vals[16];
    #pragma unroll
    for (int i = 0; i < 16; i++) vals[i] = f2bf(t[lc + i][lr]);
    uint4 pa, pb;
    pa.x = vals[0] | (vals[1] << 16);  pa.y = vals[2] | (vals[3] << 16);
    pa.z = vals[4] | (vals[5] << 16);  pa.w = vals[6] | (vals[7] << 16);
    pb.x = vals[8] | (vals[9] << 16);  pb.y = vals[10] | (vals[11] << 16);
    pb.z = vals[12] | (vals[13] << 16); pb.w = vals[14] | (vals[15] << 16);
    *(uint4*)dst = pa;
    *(uint4*)(dst + 8) = pb;
}

// ---------------- merged precompute: x->bf16 | Wq/Wk/Wv transpose | Wp transpose ----------------
__global__ __launch_bounds__(256) void cvt_all(
    const float* __restrict__ x, u16* __restrict__ xb, int n,
    const float* __restrict__ Wq, const float* __restrict__ Wk, const float* __restrict__ Wv,
    u16* __restrict__ wqt, u16* __restrict__ wkt, u16* __restrict__ wvt,
    const float* __restrict__ Wp, u16* __restrict__ wpt)
{
    const int bid = blockIdx.x;
    if (bid < 4096) {
        int i4 = (bid * 256 + threadIdx.x) * 4;
        if (i4 < n) {
            float4 f = *(const float4*)(x + i4);
            unsigned lo = (unsigned)f2bf(f.x) | ((unsigned)f2bf(f.y) << 16);
            unsigned hi = (unsigned)f2bf(f.z) | ((unsigned)f2bf(f.w) << 16);
            uint2 p; p.x = lo; p.y = hi;
            *(uint2*)(xb + i4) = p;
        }
    } else if (bid < 4096 + 768) {
        const int t  = bid - 4096;
        const int z  = t >> 4;           // 0..47
        const int ry = t & 15;           // 0..15
        const int which = z >> 4, bh = z & 15;
        const float* in = (which == 0) ? Wq : (which == 1) ? Wk : Wv;
        u16* outp = (which == 0) ? wqt : (which == 1) ? wkt : wvt;
        cvt_t_tile(in + (size_t)bh * E_DIM * D_DIM, outp + (size_t)bh * E_DIM * D_DIM,
                   E_DIM, D_DIM, ry * 64, 0);
    } else {
        const int t = bid - (4096 + 768); // 0..255
        cvt_t_tile(Wp, wpt, H_NUM * D_DIM, E_DIM, (t >> 4) * 64, (t & 15) * 64);
    }
}

// ---------------- QKV as one fused GEMM: M=4096, N=3072, K=1024, BK=64 ----------------
// Round-6: A-operand DIRECT global->register (per-lane pointers, fully-unrolled k-loop
// folds k0 into the 13-bit instruction offset; L1/L2-served), B stays LDS-staged
// (swizzled DMA, double-buffered). Splits operand traffic across the L2 and LDS pipes:
// r5's single-pipe LDS demand (~160 KB/CU/k-step, ~90% LDS-unit util) halves.
// Register prefetch ping-pongs afA/afB (named arrays -> static indexing, no scratch).
__global__ __launch_bounds__(256, 2) void qkv_gemm(
    const u16* __restrict__ xb, const u16* __restrict__ wcat,
    const float* __restrict__ bq, const float* __restrict__ bk, const float* __restrict__ bv,
    u16* __restrict__ oq, u16* __restrict__ okk, u16* __restrict__ ov)
{
    const int m0 = blockIdx.x * 128;   // 0..31
    const int n0 = blockIdx.y * 128;   // 0..23

    __shared__ u16 Bs[2][128 * 64];    // 16 KB per buffer; reused by V-transpose epilogue

    const int tid  = threadIdx.x;
    const int wave = tid >> 6, lane = tid & 63, quad = lane >> 4, l16 = lane & 15;
    const int mh = wave >> 1, nh = wave & 1;     // wave-tile 64m x 64n
    const int sr = lane >> 3, sl8 = lane & 7;    // staging geometry

    // per-lane A fragment base pointers (row m0+mh*64+mi*16+l16, col quad*8)
    const u16* aptr0 = xb + (size_t)(m0 + mh * 64 + l16) * E_DIM + quad * 8;
    const u16* aptr1 = aptr0 + 16 * E_DIM;
    const u16* aptr2 = aptr0 + 32 * E_DIM;
    const u16* aptr3 = aptr0 + 48 * E_DIM;

    f32x4 acc[4][4];
    #pragma unroll
    for (int j = 0; j < 4; j++)
        #pragma unroll
        for (int mi = 0; mi < 4; mi++) acc[j][mi] = fzero4();

#define STAGE_B(K0, BUF)                                                              \
    _Pragma("unroll")                                                                 \
    for (int i = 0; i < 4; i++) {                                                     \
        const int r  = wave * 32 + i * 8 + sr;                                        \
        const int sx = sl8 ^ (r & 7);                                                 \
        gll16(wcat + (size_t)(n0 + r) * E_DIM + (K0) + sx * 8,                        \
              &Bs[BUF][(wave * 32 + i * 8) * 64]);                                    \
    }

#define LOAD_A(DST, K0)                                                               \
    _Pragma("unroll")                                                                 \
    for (int kq = 0; kq < 2; kq++) {                                                  \
        DST[kq][0] = *(const bf16x8*)(aptr0 + (K0) + kq * 32);                        \
        DST[kq][1] = *(const bf16x8*)(aptr1 + (K0) + kq * 32);                        \
        DST[kq][2] = *(const bf16x8*)(aptr2 + (K0) + kq * 32);                        \
        DST[kq][3] = *(const bf16x8*)(aptr3 + (K0) + kq * 32);                        \
    }

#define COMPUTE(AF, BUF)                                                              \
    _Pragma("unroll")                                                                 \
    for (int kq = 0; kq < 2; kq++) {                                                  \
        __builtin_amdgcn_s_setprio(1);                                                \
        _Pragma("unroll")                                                             \
        for (int j = 0; j < 4; j++) {                                                 \
            const int rr = nh * 64 + j * 16 + l16;                                    \
            bf16x8 bfv = *(const bf16x8*)(&Bs[BUF][rr * 64 +                          \
                              (((kq << 2) + quad) ^ (rr & 7)) * 8]);                  \
            _Pragma("unroll")                                                         \
            for (int mi = 0; mi < 4; mi++)                                            \
                acc[j][mi] = MFMA16(AF[kq][mi], bfv, acc[j][mi]);                     \
        }                                                                             \
        __builtin_amdgcn_s_setprio(0);                                                \
    }

    bf16x8 afA[2][4], afB[2][4];

    // prologue: k-step 0 into buf0 / afA
    STAGE_B(0, 0);
    LOAD_A(afA, 0);

    #pragma unroll
    for (int kt2 = 0; kt2 < 8; kt2++) {
        // even step kt=2*kt2: buf0, afA; prefetch kt+1 into buf1/afB
        __syncthreads();
        {
            const int kn = kt2 * 128 + 64;
            STAGE_B(kn, 1);
            LOAD_A(afB, kn);
        }
        COMPUTE(afA, 0);

        // odd step kt=2*kt2+1: buf1, afB; prefetch kt+2 into buf0/afA
        __syncthreads();
        if (kt2 < 7) {
            const int kn = kt2 * 128 + 128;
            STAGE_B(kn, 0);
            LOAD_A(afA, kn);
        }
        COMPUTE(afB, 1);
    }
#undef STAGE_B
#undef LOAD_A
#undef COMPUTE

    const int t = n0 >> 10;            // block-uniform
    if (t < 2) {
        const float scl = (t == 0) ? QSCALE : 1.0f;
        const float* bias = (t == 0) ? bq : bk;
        u16* dst = (t == 0) ? oq : okk;
        #pragma unroll
        for (int j = 0; j < 4; j++) {
            const int n = n0 + nh * 64 + j * 16 + l16;
            const int h = (n >> 6) & 15, d = n & 63;
            float bia = bias[h * D_DIM + d];
            #pragma unroll
            for (int mi = 0; mi < 4; mi++) {
                #pragma unroll
                for (int r = 0; r < 4; r++) {
                    int m = m0 + mh * 64 + mi * 16 + quad * 4 + r;
                    int b = m >> 11, s = m & 2047;
                    dst[((size_t)(b * H_NUM + h) * S_LEN + s) * D_DIM + d] =
                        f2bf((acc[j][mi][r] + bia) * scl);
                }
            }
        }
    } else {
        // V epilogue: transpose through LDS, then coalesced [d][s] row stores.
        const int b  = m0 >> 11, s0 = m0 & 2047;
        const int h0 = (n0 >> 6) & 15;            // even; block covers heads h0, h0+1
        u16* Tb0 = Bs[0];                          // 64*72 u16 each, fits 16 KB
        u16* Tb1 = Bs[1];
        #pragma unroll
        for (int pass = 0; pass < 2; ++pass) {
            __syncthreads();
            if (mh == pass) {
                u16* Tb = nh ? Tb1 : Tb0;
                #pragma unroll
                for (int j = 0; j < 4; j++) {
                    const int n = n0 + nh * 64 + j * 16 + l16;
                    const int d = n & 63, hh = (n >> 6) & 15;
                    const float bia = bv[hh * D_DIM + d];
                    const int nl = j * 16 + l16;
                    #pragma unroll
                    for (int mi = 0; mi < 4; mi++) {
                        uint2 pk;
                        pk.x = cvtpk(acc[j][mi][0] + bia, acc[j][mi][1] + bia);
                        pk.y = cvtpk(acc[j][mi][2] + bia, acc[j][mi][3] + bia);
                        *(uint2*)(&Tb[nl * 72 + mi * 16 + quad * 4]) = pk;
                    }
                }
            }
            __syncthreads();
            #pragma unroll
            for (int g = 0; g < 4; ++g) {
                const int rowi = g * 32 + (tid >> 3);          // 0..127
                const int ml = (tid & 7) * 8;
                const u16* srcp = (rowi < 64 ? Tb0 : Tb1) + (rowi & 63) * 72 + ml;
                const int hh = h0 + (rowi >> 6), d = rowi & 63;
                u16* dstp = ov + ((size_t)(b * H_NUM + hh) * D_DIM + d) * S_LEN
                               + s0 + pass * 64 + ml;
                *(uint4*)dstp = *(const uint4*)srcp;
            }
        }
    }
}

// ---------------- flash attention (causal, S^T formulation, paired q-tiles) ----------------
// r3 structure (dual P buffers, balanced XCD decode) + T5 setprio around MFMA clusters.
__global__ __launch_bounds__(256, 2) void attn_fwd(
    const u16* __restrict__ q, const u16* __restrict__ k, const u16* __restrict__ vt,
    u16* __restrict__ concat)
{
    const int bid  = blockIdx.x;              // 0..511
    const int halfg = bid >> 8;               // 0 | 1
    const int pi   = (bid & 255) >> 5;        // 0..7
    const int p    = halfg ? (15 - pi) : pi;  // balanced: paired CUs sum to 49 iters
    const int g    = bid & 31;                // (b,h) group; XCD = g&7
    const int h    = g & 15;
    const int bb   = g >> 4;
    const int qa = p, qb = 31 - p;

    const size_t headoff = (size_t)(bb * H_NUM + h) * S_LEN * D_DIM;
    const u16* qh  = q  + headoff;
    const u16* kh  = k  + headoff;
    const u16* vth = vt + headoff;      // [D][S]

    __shared__ u16 QaL[64 * 64];
    __shared__ u16 QbL[64 * 64];
    __shared__ u16 Ks[2][64 * 64];      // [kk][d], swizzled, double-buffered
    __shared__ u16 Vts[2][64 * 64];     // [d][sk], swizzled, double-buffered
    __shared__ u16 Psa[4][16 * 72];     // per-wave P, tile a
    __shared__ u16 Psb[4][16 * 72];     // per-wave P, tile b

    const int tid  = threadIdx.x;
    const int wave = tid >> 6, lane = tid & 63, quad = lane >> 4, l16 = lane & 15;

    // ---- prologue: DMA-stage Q tiles + K/V tile 0 ----
    stage64(qh + (size_t)qa * 64 * D_DIM, D_DIM, QaL,    wave, lane);
    stage64(qh + (size_t)qb * 64 * D_DIM, D_DIM, QbL,    wave, lane);
    stage64(kh,                           D_DIM, Ks[0],  wave, lane);
    stage64(vth,                          S_LEN, Vts[0], wave, lane);
    __syncthreads();                    // drains DMA

    // Q hoisted to registers
    bf16x8 bqa0 = ldswz(QaL, wave * 16 + l16, 0, quad);
    bf16x8 bqa1 = ldswz(QaL, wave * 16 + l16, 1, quad);
    bf16x8 bqb0 = ldswz(QbL, wave * 16 + l16, 0, quad);
    bf16x8 bqb1 = ldswz(QbL, wave * 16 + l16, 1, quad);

    f32x4 oa[4], ob[4];                 // O: row=q(quad*4+r), col=d(l16)
    #pragma unroll
    for (int nt = 0; nt < 4; nt++) { oa[nt] = fzero4(); ob[nt] = fzero4(); }
    float la = 0.f, lb = 0.f;

    const int qga = qa * 64 + wave * 16 + l16;
    const int qgb = qb * 64 + wave * 16 + l16;

    u16* pwa = &Psa[wave][0];
    u16* pwb = &Psb[wave][0];

    for (int kt = 0; kt <= qb; kt++) {
        __syncthreads();                // K/V dbuf fence; drains prior DMA
        if (kt < qb) {
            stage64(kh + (size_t)(kt + 1) * 64 * D_DIM, D_DIM, Ks[(kt + 1) & 1],  wave, lane);
            stage64(vth + (kt + 1) * 64,                S_LEN, Vts[(kt + 1) & 1], wave, lane);
        }
        const u16* Kc = Ks[kt & 1];
        const u16* Vc = Vts[kt & 1];
        const bool both = (kt <= qa);

        // ---- S^T = K Q^T for both tiles (K fragments read once) ----
        f32x4 stb[4], sta[4];
        __builtin_amdgcn_s_setprio(1);
        #pragma unroll
        for (int nt = 0; nt < 4; nt++) {
            const int rr = nt * 16 + l16;
            bf16x8 ak0 = ldswz(Kc, rr, 0, quad);
            bf16x8 ak1 = ldswz(Kc, rr, 1, quad);
            stb[nt] = MFMA16(ak0, bqb0, fzero4());
            stb[nt] = MFMA16(ak1, bqb1, stb[nt]);
            if (both) {
                sta[nt] = MFMA16(ak0, bqa0, fzero4());
                sta[nt] = MFMA16(ak1, bqa1, sta[nt]);
            }
        }
        __builtin_amdgcn_s_setprio(0);

        // ---- V fragments read once, shared by both tiles ----
        bf16x8 bv0[4], bv1[4];
        #pragma unroll
        for (int nt = 0; nt < 4; nt++) {
            bv0[nt] = ldswz(Vc, nt * 16 + l16, 0, quad);
            bv1[nt] = ldswz(Vc, nt * 16 + l16, 1, quad);
        }

        // ---- exp + P write, tile b then tile a (independent buffers -> overlap) ----
        #pragma unroll
        for (int nt = 0; nt < 4; nt++) {
            float pe[4];
            if (kt == qb) {
                #pragma unroll
                for (int r = 0; r < 4; r++) {
                    int kkg = kt * 64 + nt * 16 + quad * 4 + r;
                    pe[r] = (kkg > qgb) ? 0.f : fexp2(stb[nt][r]);
                }
            } else {
                #pragma unroll
                for (int r = 0; r < 4; r++) pe[r] = fexp2(stb[nt][r]);
            }
            lb += (pe[0] + pe[1]) + (pe[2] + pe[3]);
            uint2 pk;
            pk.x = cvtpk(pe[0], pe[1]);
            pk.y = cvtpk(pe[2], pe[3]);
            *(uint2*)(&pwb[l16 * 72 + nt * 16 + quad * 4]) = pk;
        }
        if (both) {
            #pragma unroll
            for (int nt = 0; nt < 4; nt++) {
                float pe[4];
                if (kt == qa) {
                    #pragma unroll
                    for (int r = 0; r < 4; r++) {
                        int kkg = kt * 64 + nt * 16 + quad * 4 + r;
                        pe[r] = (kkg > qga) ? 0.f : fexp2(sta[nt][r]);
                    }
                } else {
                    #pragma unroll
                    for (int r = 0; r < 4; r++) pe[r] = fexp2(sta[nt][r]);
                }
                la += (pe[0] + pe[1]) + (pe[2] + pe[3]);
                uint2 pk;
                pk.x = cvtpk(pe[0], pe[1]);
                pk.y = cvtpk(pe[2], pe[3]);
                *(uint2*)(&pwa[l16 * 72 + nt * 16 + quad * 4]) = pk;
            }
        }

        // ---- PV, tile b then tile a (b's MFMAs hide a's P read) ----
        {
            bf16x8 ap0 = *(const bf16x8*)(&pwb[l16 * 72 + quad * 8]);
            bf16x8 ap1 = *(const bf16x8*)(&pwb[l16 * 72 + 32 + quad * 8]);
            __builtin_amdgcn_s_setprio(1);
            #pragma unroll
            for (int nt = 0; nt < 4; nt++) {
                ob[nt] = MFMA16(ap0, bv0[nt], ob[nt]);
                ob[nt] = MFMA16(ap1, bv1[nt], ob[nt]);
            }
            __builtin_amdgcn_s_setprio(0);
        }
        if (both) {
            bf16x8 ap0 = *(const bf16x8*)(&pwa[l16 * 72 + quad * 8]);
            bf16x8 ap1 = *(const bf16x8*)(&pwa[l16 * 72 + 32 + quad * 8]);
            __builtin_amdgcn_s_setprio(1);
            #pragma unroll
            for (int nt = 0; nt < 4; nt++) {
                oa[nt] = MFMA16(ap0, bv0[nt], oa[nt]);
                oa[nt] = MFMA16(ap1, bv1[nt], oa[nt]);
            }
            __builtin_amdgcn_s_setprio(0);
        }
    }

    // ---- epilogue: row-sum reduce + normalized store ----
    lb += __shfl_xor(lb, 16); lb += __shfl_xor(lb, 32);
    la += __shfl_xor(la, 16); la += __shfl_xor(la, 32);

    #pragma unroll
    for (int r = 0; r < 4; r++) {
        const int srcl = quad * 4 + r;
        float lbi = frcp(__shfl(lb, srcl));
        float lai = frcp(__shfl(la, srcl));
        int sqa = qa * 64 + wave * 16 + quad * 4 + r;
        int sqb = qb * 64 + wave * 16 + quad * 4 + r;
        #pragma unroll
        for (int nt = 0; nt < 4; nt++) {
            concat[((size_t)(bb * S_LEN + sqa)) * E_DIM + h * D_DIM + nt * 16 + l16] =
                f2bf(oa[nt][r] * lai);
            concat[((size_t)(bb * S_LEN + sqb)) * E_DIM + h * D_DIM + nt * 16 + l16] =
                f2bf(ob[nt][r] * lbi);
        }
    }
}

// ---------------- output projection: 64m x 128n tiles, 512 blocks (2/CU) ----------------
// DMA staging (stage64/ldswz), double-buffered, 1 barrier/iter with DMA-under-compute.
// wpt: [E(n)][HD(k)] bf16
__global__ __launch_bounds__(256, 2) void out_proj(
    const u16* __restrict__ concat, const u16* __restrict__ wpt,
    const float* __restrict__ bp, float* __restrict__ out)
{
    const int bid = blockIdx.x;                        // 0..511
    const int mt  = (bid & 7) * 8 + ((bid >> 3) & 7);  // m-tile 0..63
    const int nt0 = bid >> 6;                          // n-tile 0..7
    const int m0 = mt * 64;
    const int n0 = nt0 * 128;

    __shared__ u16 As[2][64 * 64];      // A: 64 m-rows x 64 k, swizzled, dbuf (8 KB each)
    __shared__ u16 Bs[2][128 * 64];     // B: 128 n-rows x 64 k, swizzled, dbuf (16 KB each)

    const int tid  = threadIdx.x;
    const int wave = tid >> 6, lane = tid & 63, quad = lane >> 4, l16 = lane & 15;
    const int mh = wave >> 1, nh = wave & 1;           // wave-tile 32m x 64n

    f32x4 acc[4][2];                    // [j=n-frag][mi=m-frag]
    #pragma unroll
    for (int j = 0; j < 4; j++)
        #pragma unroll
        for (int mi = 0; mi < 2; mi++) acc[j][mi] = fzero4();

    // prologue: stage k-tile 0
    stage64(concat + (size_t)m0 * E_DIM, E_DIM, As[0], wave, lane);
    stage64(wpt + (size_t)n0 * E_DIM,        E_DIM, Bs[0],           wave, lane);
    stage64(wpt + (size_t)(n0 + 64) * E_DIM, E_DIM, Bs[0] + 64 * 64, wave, lane);

    for (int kt = 0; kt < 16; kt++) {
        __syncthreads();                // drains DMA of buf[kt&1]; fences reads of buf[(kt+1)&1]
        if (kt < 15) {
            const int k0 = (kt + 1) * 64;
            u16* an = As[(kt + 1) & 1];
            u16* bn = Bs[(kt + 1) & 1];
            stage64(concat + (size_t)m0 * E_DIM + k0, E_DIM, an, wave, lane);
            stage64(wpt + (size_t)n0 * E_DIM + k0,        E_DIM, bn,           wave, lane);
            stage64(wpt + (size_t)(n0 + 64) * E_DIM + k0, E_DIM, bn + 64 * 64, wave, lane);
        }
        const u16* Ac = As[kt & 1];
        const u16* Bc = Bs[kt & 1];

        #pragma unroll
        for (int kq = 0; kq < 2; kq++) {
            bf16x8 af[2];
            #pragma unroll
            for (int mi = 0; mi < 2; mi++)
                af[mi] = ldswz(Ac, mh * 32 + mi * 16 + l16, kq, quad);
            __builtin_amdgcn_s_setprio(1);
            #pragma unroll
            for (int j = 0; j < 4; j++) {
                bf16x8 bfv = ldswz(Bc, nh * 64 + j * 16 + l16, kq, quad);
                #pragma unroll
                for (int mi = 0; mi < 2; mi++)
                    acc[j][mi] = MFMA16(af[mi], bfv, acc[j][mi]);
            }
            __builtin_amdgcn_s_setprio(0);
        }
    }

    #pragma unroll
    for (int j = 0; j < 4; j++) {
        int n = n0 + nh * 64 + j * 16 + l16;
        float bia = bp[n];
        #pragma unroll
        for (int mi = 0; mi < 2; mi++) {
            #pragma unroll
            for (int r = 0; r < 4; r++) {
                int m = m0 + mh * 32 + mi * 16 + quad * 4 + r;
                out[(size_t)m * E_DIM + n] = fmaxf(acc[j][mi][r] + bia, 0.f);
            }
        }
    }
}

extern "C" void kernel_launch(void* const* d_in, const int* in_sizes, int n_in,
                              void* d_out, int out_size, void* d_ws, size_t ws_size,
                              hipStream_t stream)
{
    (void)in_sizes; (void)n_in; (void)out_size; (void)ws_size;
    const float* x  = (const float*)d_in[0];
    const float* Wq = (const float*)d_in[1];
    const float* Wk = (const float*)d_in[2];
    const float* Wv = (const float*)d_in[3];
    const float* bq = (const float*)d_in[4];
    const float* bk = (const float*)d_in[5];
    const float* bv = (const float*)d_in[6];
    const float* Wp = (const float*)d_in[7];
    const float* bp = (const float*)d_in[8];
    float* out = (float*)d_out;

    const size_t QKV_ELEMS = (size_t)2 * H_NUM * S_LEN * D_DIM;  // 4,194,304
    const size_t W_ELEMS   = (size_t)H_NUM * E_DIM * D_DIM;      // 1,048,576

    u16* q   = (u16*)d_ws;
    u16* k   = q   + QKV_ELEMS;
    u16* v   = k   + QKV_ELEMS;       // V^T [B,H,D,S], written directly by qkv_gemm
    u16* cc  = v   + QKV_ELEMS;
    u16* xb  = cc  + QKV_ELEMS;       // x bf16
    u16* wqt = xb  + QKV_ELEMS;       // [H][D][E] bf16  -- wqt||wkt||wvt = wcat [3072][1024]
    u16* wkt = wqt + W_ELEMS;
    u16* wvt = wkt + W_ELEMS;
    u16* wpt = wvt + W_ELEMS;         // [E][HD] bf16

    cvt_all<<<dim3(4096 + 768 + 256), 256, 0, stream>>>(
        x, xb, (int)QKV_ELEMS, Wq, Wk, Wv, wqt, wkt, wvt, Wp, wpt);

    qkv_gemm<<<dim3(32, 24), 256, 0, stream>>>(xb, wqt, bq, bk, bv, q, k, v);
    attn_fwd<<<dim3(512), 256, 0, stream>>>(q, k, v, cc);
    out_proj<<<dim3(512), 256, 0, stream>>>(cc, wpt, bp, out);
}

// Round 7
// 175.306 us; speedup vs baseline: 1.1261x; 1.1261x over previous
//
#include <hip/hip_runtime.h>

#define S_LEN 2048
#define E_DIM 1024
#define H_NUM 16
#define D_DIM 64

typedef unsigned short u16;
using bf16x8 = __attribute__((ext_vector_type(8))) short;   // 8 bf16 in 4 VGPRs
using f32x4  = __attribute__((ext_vector_type(4))) float;

#define MFMA16(A, B, C) __builtin_amdgcn_mfma_f32_16x16x32_bf16(A, B, C, 0, 0, 0)
#define QSCALE 0.18033688011112042f   // (1/sqrt(D)) * log2(e), folded into Q so attn uses exp2

__device__ __forceinline__ u16 f2bf(float f) {
    unsigned u = __float_as_uint(f);
    u += 0x7fffu + ((u >> 16) & 1u);            // RNE
    return (u16)(u >> 16);
}
__device__ __forceinline__ f32x4 fzero4() { f32x4 z; z[0]=0.f; z[1]=0.f; z[2]=0.f; z[3]=0.f; return z; }

// packed f32x2 -> bf16x2 (RNE)
__device__ __forceinline__ unsigned cvtpk(float a, float b) {
    unsigned r;
    asm("v_cvt_pk_bf16_f32 %0, %1, %2" : "=v"(r) : "v"(a), "v"(b));
    return r;
}
__device__ __forceinline__ float fexp2(float x) {
#if __has_builtin(__builtin_amdgcn_exp2f)
    return __builtin_amdgcn_exp2f(x);
#else
    float r; asm("v_exp_f32 %0, %1" : "=v"(r) : "v"(x)); return r;
#endif
}
__device__ __forceinline__ float frcp(float x) {
#if __has_builtin(__builtin_amdgcn_rcpf)
    return __builtin_amdgcn_rcpf(x);
#else
    float r; asm("v_rcp_f32 %0, %1" : "=v"(r) : "v"(x)); return r;
#endif
}

// async global->LDS, 16B per lane; LDS dest = wave-uniform base + lane*16
__device__ __forceinline__ void gll16(const u16* g, u16* l) {
    __builtin_amdgcn_global_load_lds(
        (const __attribute__((address_space(1))) void*)g,
        (__attribute__((address_space(3))) void*)l, 16, 0, 0);
}

// ---- swizzled 64x64 u16 tile staging via global_load_lds (both-sides XOR swizzle) ----
// LDS row r at bytes r*128; physical 16B slot s holds logical slot s^(r&7).
__device__ __forceinline__ void stage64(const u16* __restrict__ g, int gstride,
                                        u16* l, int wave, int lane) {
    #pragma unroll
    for (int i = 0; i < 2; i++) {
        const int r  = wave * 16 + i * 8 + (lane >> 3);
        const int sl = (lane & 7) ^ (r & 7);
        gll16(g + (size_t)r * gstride + sl * 8, l + (wave * 16 + i * 8) * 64);
    }
}
// read one bf16x8 fragment = logical u16 cols [(hh*4+quad)*8 .. +7] of row rr
__device__ __forceinline__ bf16x8 ldswz(const u16* t, int rr, int hh, int quad) {
    const int sl = ((hh << 2) + quad) ^ (rr & 7);
    return *(const bf16x8*)(t + rr * 64 + sl * 8);
}

// ---------------- fp32 [R,C] tile -> bf16 [C,R] transpose-convert helper ----------------
__device__ __forceinline__ void cvt_t_tile(const float* __restrict__ bin, u16* __restrict__ bout,
                                           int R, int C, int r0, int c0) {
    __shared__ float t[64][65];
    const int tid = threadIdx.x;
    const int lr = tid >> 2, lc = (tid & 3) * 16;

    const float* src = bin + (size_t)(r0 + lr) * C + c0 + lc;
    #pragma unroll
    for (int j = 0; j < 4; j++) {
        float4 f = *(const float4*)(src + j * 4);
        t[lr][lc + j * 4 + 0] = f.x; t[lr][lc + j * 4 + 1] = f.y;
        t[lr][lc + j * 4 + 2] = f.z; t[lr][lc + j * 4 + 3] = f.w;
    }
    __syncthreads();

    u16* dst = bout + (size_t)(c0 + lr) * R + r0 + lc;
    u16 vals[16];
    #pragma unroll
    for (int i = 0; i < 16; i++) vals[i] = f2bf(t[lc + i][lr]);
    uint4 pa, pb;
    pa.x = vals[0] | (vals[1] << 16);  pa.y = vals[2] | (vals[3] << 16);
    pa.z = vals[4] | (vals[5] << 16);  pa.w = vals[6] | (vals[7] << 16);
    pb.x = vals[8] | (vals[9] << 16);  pb.y = vals[10] | (vals[11] << 16);
    pb.z = vals[12] | (vals[13] << 16); pb.w = vals[14] | (vals[15] << 16);
    *(uint4*)dst = pa;
    *(uint4*)(dst + 8) = pb;
}

// ---------------- merged precompute: x->bf16 | Wq/Wk/Wv transpose | Wp transpose ----------------
__global__ __launch_bounds__(256) void cvt_all(
    const float* __restrict__ x, u16* __restrict__ xb, int n,
    const float* __restrict__ Wq, const float* __restrict__ Wk, const float* __restrict__ Wv,
    u16* __restrict__ wqt, u16* __restrict__ wkt, u16* __restrict__ wvt,
    const float* __restrict__ Wp, u16* __restrict__ wpt)
{
    const int bid = blockIdx.x;
    if (bid < 4096) {
        int i4 = (bid * 256 + threadIdx.x) * 4;
        if (i4 < n) {
            float4 f = *(const float4*)(x + i4);
            unsigned lo = (unsigned)f2bf(f.x) | ((unsigned)f2bf(f.y) << 16);
            unsigned hi = (unsigned)f2bf(f.z) | ((unsigned)f2bf(f.w) << 16);
            uint2 p; p.x = lo; p.y = hi;
            *(uint2*)(xb + i4) = p;
        }
    } else if (bid < 4096 + 768) {
        const int t  = bid - 4096;
        const int z  = t >> 4;           // 0..47
        const int ry = t & 15;           // 0..15
        const int which = z >> 4, bh = z & 15;
        const float* in = (which == 0) ? Wq : (which == 1) ? Wk : Wv;
        u16* outp = (which == 0) ? wqt : (which == 1) ? wkt : wvt;
        cvt_t_tile(in + (size_t)bh * E_DIM * D_DIM, outp + (size_t)bh * E_DIM * D_DIM,
                   E_DIM, D_DIM, ry * 64, 0);
    } else {
        const int t = bid - (4096 + 768); // 0..255
        cvt_t_tile(Wp, wpt, H_NUM * D_DIM, E_DIM, (t >> 4) * 64, (t & 15) * 64);
    }
}

// ---------------- QKV as one fused GEMM: M=4096, N=3072, K=1024 ----------------
// Round-7: LDS-bytes/FLOP cut. Block 128x128, TWO waves (128 thr), wave-tile 64m x 128n,
// BK=32, double-buffered, 4 blocks/CU. Per wave: 12 ds_read_b128 feed 32 MFMAs
// (vs r5: 8 feed 16) -> total LDS traffic 45.7 -> 38.1 KB/MFLOP. LDS tile packs
// m-rows {r, r+64} into one 128B row so the verified 8-slot XOR swizzle + wave-uniform
// DMA staging carry over: slot = (half<<2 | quad) ^ (row&7). Natural dispatch (r5 lesson).
__global__ __launch_bounds__(128, 2) void qkv_gemm(
    const u16* __restrict__ xb, const u16* __restrict__ wcat,
    const float* __restrict__ bq, const float* __restrict__ bk, const float* __restrict__ bv,
    u16* __restrict__ oq, u16* __restrict__ okk, u16* __restrict__ ov)
{
    const int m0 = blockIdx.x * 128;   // 0..31
    const int n0 = blockIdx.y * 128;   // 0..23

    // 64 LDS-rows x 128B; row r holds {m-row r (slots 0-3), m-row r+64 (slots 4-7)} x 32k
    __shared__ u16 As[2][64 * 64];     // 8 KB per buffer
    __shared__ u16 Bs[2][64 * 64];

    const int tid  = threadIdx.x;      // 0..127
    const int wave = tid >> 6, lane = tid & 63, quad = lane >> 4, l16 = lane & 15;

    f32x4 acc[8][4];                   // [j=n-frag 0..7][mi=m-frag 0..3]
    #pragma unroll
    for (int j = 0; j < 8; j++)
        #pragma unroll
        for (int mi = 0; mi < 4; mi++) acc[j][mi] = fzero4();

#define STAGE(K0, BUF)                                                               \
    _Pragma("unroll")                                                                \
    for (int i = 0; i < 2; i++) {                                                    \
        const int r  = wave * 32 + i * 8 + (lane >> 3);   /* LDS row 0..63 */        \
        const int s  = (lane & 7) ^ (r & 7);              /* logical slot  */        \
        const int mr = r + ((s >> 2) << 6);               /* m/n-row 0..127 */       \
        const int kc = (s & 3) * 8;                       /* k-col base     */       \
        gll16(xb   + (size_t)(m0 + mr) * E_DIM + (K0) + kc,                          \
              &As[BUF][(wave * 32 + i * 8) * 64]);                                   \
        gll16(wcat + (size_t)(n0 + mr) * E_DIM + (K0) + kc,                          \
              &Bs[BUF][(wave * 32 + i * 8) * 64]);                                   \
        const int r2  = wave * 32 + 16 + i * 8 + (lane >> 3);                        \
        const int s2  = (lane & 7) ^ (r2 & 7);                                       \
        const int mr2 = r2 + ((s2 >> 2) << 6);                                       \
        const int kc2 = (s2 & 3) * 8;                                                \
        gll16(xb   + (size_t)(m0 + mr2) * E_DIM + (K0) + kc2,                        \
              &As[BUF][(wave * 32 + 16 + i * 8) * 64]);                              \
        gll16(wcat + (size_t)(n0 + mr2) * E_DIM + (K0) + kc2,                        \
              &Bs[BUF][(wave * 32 + 16 + i * 8) * 64]);                              \
    }

    // prologue: stage k-tile 0 into buffer 0
    STAGE(0, 0);

    for (int kt = 0; kt < 32; kt++) {
        __syncthreads();               // drains DMA for buf[kt&1]; fences reads of other buf
        if (kt < 31) {
            const int kn = (kt + 1) * 32;
            if ((kt & 1) == 0) { STAGE(kn, 1); } else { STAGE(kn, 0); }
        }
        const u16* Ac = As[kt & 1];
        const u16* Bc = Bs[kt & 1];

        // A frags: m-row = wave*64 + mi*16 + l16 -> LDS row mi*16+l16, half=wave
        bf16x8 af[4];
        #pragma unroll
        for (int mi = 0; mi < 4; mi++) {
            const int row = mi * 16 + l16;
            af[mi] = *(const bf16x8*)(&Ac[row * 64 + ((((wave << 2) + quad)) ^ (row & 7)) * 8]);
        }
        __builtin_amdgcn_s_setprio(1);
        #pragma unroll
        for (int j = 0; j < 8; j++) {
            const int row = (j & 3) * 16 + l16;           // n-row j*16+l16 -> half = j>>2
            bf16x8 bfv = *(const bf16x8*)(&Bc[row * 64 +
                              ((((j >> 2) << 2) + quad) ^ (row & 7)) * 8]);
            #pragma unroll
            for (int mi = 0; mi < 4; mi++)
                acc[j][mi] = MFMA16(af[mi], bfv, acc[j][mi]);
        }
        __builtin_amdgcn_s_setprio(0);
    }
#undef STAGE

    const int t = n0 >> 10;            // block-uniform (1024 % 128 == 0, no straddle)
    if (t < 2) {
        const float scl = (t == 0) ? QSCALE : 1.0f;
        const float* bias = (t == 0) ? bq : bk;
        u16* dst = (t == 0) ? oq : okk;
        #pragma unroll
        for (int j = 0; j < 8; j++) {
            const int n = n0 + j * 16 + l16;
            const int h = (n >> 6) & 15, d = n & 63;
            float bia = bias[h * D_DIM + d];
            #pragma unroll
            for (int mi = 0; mi < 4; mi++) {
                #pragma unroll
                for (int r = 0; r < 4; r++) {
                    int m = m0 + wave * 64 + mi * 16 + quad * 4 + r;
                    int b = m >> 11, s = m & 2047;
                    dst[((size_t)(b * H_NUM + h) * S_LEN + s) * D_DIM + d] =
                        f2bf((acc[j][mi][r] + bia) * scl);
                }
            }
        }
    } else {
        // V epilogue: transpose through LDS, then coalesced [d][s] row stores.
        // Tb0 = As block (16 KB, holds 64x72 u16), Tb1 = Bs block.
        const int b  = m0 >> 11, s0 = m0 & 2047;
        const int h0 = (n0 >> 6) & 15;            // even; block covers heads h0, h0+1
        u16* Tb0 = &As[0][0];
        u16* Tb1 = &Bs[0][0];
        #pragma unroll
        for (int pass = 0; pass < 2; ++pass) {     // pass = which wave's m-half
            __syncthreads();
            if (wave == pass) {
                #pragma unroll
                for (int j = 0; j < 8; j++) {
                    const int n = n0 + j * 16 + l16;
                    const int d = n & 63, hh = (n >> 6) & 15;
                    const float bia = bv[hh * D_DIM + d];
                    u16* Tb = (j < 4) ? Tb0 : Tb1;
                    const int nl = (j & 3) * 16 + l16;
                    #pragma unroll
                    for (int mi = 0; mi < 4; mi++) {
                        uint2 pk;
                        pk.x = cvtpk(acc[j][mi][0] + bia, acc[j][mi][1] + bia);
                        pk.y = cvtpk(acc[j][mi][2] + bia, acc[j][mi][3] + bia);
                        *(uint2*)(&Tb[nl * 72 + mi * 16 + quad * 4]) = pk;
                    }
                }
            }
            __syncthreads();
            #pragma unroll
            for (int g = 0; g < 8; ++g) {
                const int rowi = g * 16 + (tid >> 3);          // n-local 0..127
                const int ml = (tid & 7) * 8;
                const u16* srcp = (rowi < 64 ? Tb0 : Tb1) + (rowi & 63) * 72 + ml;
                const int hh = h0 + (rowi >> 6), d = rowi & 63;
                u16* dstp = ov + ((size_t)(b * H_NUM + hh) * D_DIM + d) * S_LEN
                               + s0 + pass * 64 + ml;
                *(uint4*)dstp = *(const uint4*)srcp;
            }
        }
    }
}

// ---------------- flash attention (causal, S^T formulation, paired q-tiles) ----------------
// r3 structure (dual P buffers, balanced XCD decode) + T5 setprio around MFMA clusters.
__global__ __launch_bounds__(256, 2) void attn_fwd(
    const u16* __restrict__ q, const u16* __restrict__ k, const u16* __restrict__ vt,
    u16* __restrict__ concat)
{
    const int bid  = blockIdx.x;              // 0..511
    const int halfg = bid >> 8;               // 0 | 1
    const int pi   = (bid & 255) >> 5;        // 0..7
    const int p    = halfg ? (15 - pi) : pi;  // balanced: paired CUs sum to 49 iters
    const int g    = bid & 31;                // (b,h) group; XCD = g&7
    const int h    = g & 15;
    const int bb   = g >> 4;
    const int qa = p, qb = 31 - p;

    const size_t headoff = (size_t)(bb * H_NUM + h) * S_LEN * D_DIM;
    const u16* qh  = q  + headoff;
    const u16* kh  = k  + headoff;
    const u16* vth = vt + headoff;      // [D][S]

    __shared__ u16 QaL[64 * 64];
    __shared__ u16 QbL[64 * 64];
    __shared__ u16 Ks[2][64 * 64];      // [kk][d], swizzled, double-buffered
    __shared__ u16 Vts[2][64 * 64];     // [d][sk], swizzled, double-buffered
    __shared__ u16 Psa[4][16 * 72];     // per-wave P, tile a
    __shared__ u16 Psb[4][16 * 72];     // per-wave P, tile b

    const int tid  = threadIdx.x;
    const int wave = tid >> 6, lane = tid & 63, quad = lane >> 4, l16 = lane & 15;

    // ---- prologue: DMA-stage Q tiles + K/V tile 0 ----
    stage64(qh + (size_t)qa * 64 * D_DIM, D_DIM, QaL,    wave, lane);
    stage64(qh + (size_t)qb * 64 * D_DIM, D_DIM, QbL,    wave, lane);
    stage64(kh,                           D_DIM, Ks[0],  wave, lane);
    stage64(vth,                          S_LEN, Vts[0], wave, lane);
    __syncthreads();                    // drains DMA

    // Q hoisted to registers
    bf16x8 bqa0 = ldswz(QaL, wave * 16 + l16, 0, quad);
    bf16x8 bqa1 = ldswz(QaL, wave * 16 + l16, 1, quad);
    bf16x8 bqb0 = ldswz(QbL, wave * 16 + l16, 0, quad);
    bf16x8 bqb1 = ldswz(QbL, wave * 16 + l16, 1, quad);

    f32x4 oa[4], ob[4];                 // O: row=q(quad*4+r), col=d(l16)
    #pragma unroll
    for (int nt = 0; nt < 4; nt++) { oa[nt] = fzero4(); ob[nt] = fzero4(); }
    float la = 0.f, lb = 0.f;

    const int qga = qa * 64 + wave * 16 + l16;
    const int qgb = qb * 64 + wave * 16 + l16;

    u16* pwa = &Psa[wave][0];
    u16* pwb = &Psb[wave][0];

    for (int kt = 0; kt <= qb; kt++) {
        __syncthreads();                // K/V dbuf fence; drains prior DMA
        if (kt < qb) {
            stage64(kh + (size_t)(kt + 1) * 64 * D_DIM, D_DIM, Ks[(kt + 1) & 1],  wave, lane);
            stage64(vth + (kt + 1) * 64,                S_LEN, Vts[(kt + 1) & 1], wave, lane);
        }
        const u16* Kc = Ks[kt & 1];
        const u16* Vc = Vts[kt & 1];
        const bool both = (kt <= qa);

        // ---- S^T = K Q^T for both tiles (K fragments read once) ----
        f32x4 stb[4], sta[4];
        __builtin_amdgcn_s_setprio(1);
        #pragma unroll
        for (int nt = 0; nt < 4; nt++) {
            const int rr = nt * 16 + l16;
            bf16x8 ak0 = ldswz(Kc, rr, 0, quad);
            bf16x8 ak1 = ldswz(Kc, rr, 1, quad);
            stb[nt] = MFMA16(ak0, bqb0, fzero4());
            stb[nt] = MFMA16(ak1, bqb1, stb[nt]);
            if (both) {
                sta[nt] = MFMA16(ak0, bqa0, fzero4());
                sta[nt] = MFMA16(ak1, bqa1, sta[nt]);
            }
        }
        __builtin_amdgcn_s_setprio(0);

        // ---- V fragments read once, shared by both tiles ----
        bf16x8 bv0[4], bv1[4];
        #pragma unroll
        for (int nt = 0; nt < 4; nt++) {
            bv0[nt] = ldswz(Vc, nt * 16 + l16, 0, quad);
            bv1[nt] = ldswz(Vc, nt * 16 + l16, 1, quad);
        }

        // ---- exp + P write, tile b then tile a (independent buffers -> overlap) ----
        #pragma unroll
        for (int nt = 0; nt < 4; nt++) {
            float pe[4];
            if (kt == qb) {
                #pragma unroll
                for (int r = 0; r < 4; r++) {
                    int kkg = kt * 64 + nt * 16 + quad * 4 + r;
                    pe[r] = (kkg > qgb) ? 0.f : fexp2(stb[nt][r]);
                }
            } else {
                #pragma unroll
                for (int r = 0; r < 4; r++) pe[r] = fexp2(stb[nt][r]);
            }
            lb += (pe[0] + pe[1]) + (pe[2] + pe[3]);
            uint2 pk;
            pk.x = cvtpk(pe[0], pe[1]);
            pk.y = cvtpk(pe[2], pe[3]);
            *(uint2*)(&pwb[l16 * 72 + nt * 16 + quad * 4]) = pk;
        }
        if (both) {
            #pragma unroll
            for (int nt = 0; nt < 4; nt++) {
                float pe[4];
                if (kt == qa) {
                    #pragma unroll
                    for (int r = 0; r < 4; r++) {
                        int kkg = kt * 64 + nt * 16 + quad * 4 + r;
                        pe[r] = (kkg > qga) ? 0.f : fexp2(sta[nt][r]);
                    }
                } else {
                    #pragma unroll
                    for (int r = 0; r < 4; r++) pe[r] = fexp2(sta[nt][r]);
                }
                la += (pe[0] + pe[1]) + (pe[2] + pe[3]);
                uint2 pk;
                pk.x = cvtpk(pe[0], pe[1]);
                pk.y = cvtpk(pe[2], pe[3]);
                *(uint2*)(&pwa[l16 * 72 + nt * 16 + quad * 4]) = pk;
            }
        }

        // ---- PV, tile b then tile a (b's MFMAs hide a's P read) ----
        {
            bf16x8 ap0 = *(const bf16x8*)(&pwb[l16 * 72 + quad * 8]);
            bf16x8 ap1 = *(const bf16x8*)(&pwb[l16 * 72 + 32 + quad * 8]);
            __builtin_amdgcn_s_setprio(1);
            #pragma unroll
            for (int nt = 0; nt < 4; nt++) {
                ob[nt] = MFMA16(ap0, bv0[nt], ob[nt]);
                ob[nt] = MFMA16(ap1, bv1[nt], ob[nt]);
            }
            __builtin_amdgcn_s_setprio(0);
        }
        if (both) {
            bf16x8 ap0 = *(const bf16x8*)(&pwa[l16 * 72 + quad * 8]);
            bf16x8 ap1 = *(const bf16x8*)(&pwa[l16 * 72 + 32 + quad * 8]);
            __builtin_amdgcn_s_setprio(1);
            #pragma unroll
            for (int nt = 0; nt < 4; nt++) {
                oa[nt] = MFMA16(ap0, bv0[nt], oa[nt]);
                oa[nt] = MFMA16(ap1, bv1[nt], oa[nt]);
            }
            __builtin_amdgcn_s_setprio(0);
        }
    }

    // ---- epilogue: row-sum reduce + normalized store ----
    lb += __shfl_xor(lb, 16); lb += __shfl_xor(lb, 32);
    la += __shfl_xor(la, 16); la += __shfl_xor(la, 32);

    #pragma unroll
    for (int r = 0; r < 4; r++) {
        const int srcl = quad * 4 + r;
        float lbi = frcp(__shfl(lb, srcl));
        float lai = frcp(__shfl(la, srcl));
        int sqa = qa * 64 + wave * 16 + quad * 4 + r;
        int sqb = qb * 64 + wave * 16 + quad * 4 + r;
        #pragma unroll
        for (int nt = 0; nt < 4; nt++) {
            concat[((size_t)(bb * S_LEN + sqa)) * E_DIM + h * D_DIM + nt * 16 + l16] =
                f2bf(oa[nt][r] * lai);
            concat[((size_t)(bb * S_LEN + sqb)) * E_DIM + h * D_DIM + nt * 16 + l16] =
                f2bf(ob[nt][r] * lbi);
        }
    }
}

// ---------------- output projection: 64m x 128n tiles, 512 blocks (2/CU) ----------------
// DMA staging (stage64/ldswz), double-buffered, 1 barrier/iter with DMA-under-compute.
// wpt: [E(n)][HD(k)] bf16
__global__ __launch_bounds__(256, 2) void out_proj(
    const u16* __restrict__ concat, const u16* __restrict__ wpt,
    const float* __restrict__ bp, float* __restrict__ out)
{
    const int bid = blockIdx.x;                        // 0..511
    const int mt  = (bid & 7) * 8 + ((bid >> 3) & 7);  // m-tile 0..63
    const int nt0 = bid >> 6;                          // n-tile 0..7
    const int m0 = mt * 64;
    const int n0 = nt0 * 128;

    __shared__ u16 As[2][64 * 64];      // A: 64 m-rows x 64 k, swizzled, dbuf (8 KB each)
    __shared__ u16 Bs[2][128 * 64];     // B: 128 n-rows x 64 k, swizzled, dbuf (16 KB each)

    const int tid  = threadIdx.x;
    const int wave = tid >> 6, lane = tid & 63, quad = lane >> 4, l16 = lane & 15;
    const int mh = wave >> 1, nh = wave & 1;           // wave-tile 32m x 64n

    f32x4 acc[4][2];                    // [j=n-frag][mi=m-frag]
    #pragma unroll
    for (int j = 0; j < 4; j++)
        #pragma unroll
        for (int mi = 0; mi < 2; mi++) acc[j][mi] = fzero4();

    // prologue: stage k-tile 0
    stage64(concat + (size_t)m0 * E_DIM, E_DIM, As[0], wave, lane);
    stage64(wpt + (size_t)n0 * E_DIM,        E_DIM, Bs[0],           wave, lane);
    stage64(wpt + (size_t)(n0 + 64) * E_DIM, E_DIM, Bs[0] + 64 * 64, wave, lane);

    for (int kt = 0; kt < 16; kt++) {
        __syncthreads();                // drains DMA of buf[kt&1]; fences reads of buf[(kt+1)&1]
        if (kt < 15) {
            const int k0 = (kt + 1) * 64;
            u16* an = As[(kt + 1) & 1];
            u16* bn = Bs[(kt + 1) & 1];
            stage64(concat + (size_t)m0 * E_DIM + k0, E_DIM, an, wave, lane);
            stage64(wpt + (size_t)n0 * E_DIM + k0,        E_DIM, bn,           wave, lane);
            stage64(wpt + (size_t)(n0 + 64) * E_DIM + k0, E_DIM, bn + 64 * 64, wave, lane);
        }
        const u16* Ac = As[kt & 1];
        const u16* Bc = Bs[kt & 1];

        #pragma unroll
        for (int kq = 0; kq < 2; kq++) {
            bf16x8 af[2];
            #pragma unroll
            for (int mi = 0; mi < 2; mi++)
                af[mi] = ldswz(Ac, mh * 32 + mi * 16 + l16, kq, quad);
            __builtin_amdgcn_s_setprio(1);
            #pragma unroll
            for (int j = 0; j < 4; j++) {
                bf16x8 bfv = ldswz(Bc, nh * 64 + j * 16 + l16, kq, quad);
                #pragma unroll
                for (int mi = 0; mi < 2; mi++)
                    acc[j][mi] = MFMA16(af[mi], bfv, acc[j][mi]);
            }
            __builtin_amdgcn_s_setprio(0);
        }
    }

    #pragma unroll
    for (int j = 0; j < 4; j++) {
        int n = n0 + nh * 64 + j * 16 + l16;
        float bia = bp[n];
        #pragma unroll
        for (int mi = 0; mi < 2; mi++) {
            #pragma unroll
            for (int r = 0; r < 4; r++) {
                int m = m0 + mh * 32 + mi * 16 + quad * 4 + r;
                out[(size_t)m * E_DIM + n] = fmaxf(acc[j][mi][r] + bia, 0.f);
            }
        }
    }
}

extern "C" void kernel_launch(void* const* d_in, const int* in_sizes, int n_in,
                              void* d_out, int out_size, void* d_ws, size_t ws_size,
                              hipStream_t stream)
{
    (void)in_sizes; (void)n_in; (void)out_size; (void)ws_size;
    const float* x  = (const float*)d_in[0];
    const float* Wq = (const float*)d_in[1];
    const float* Wk = (const float*)d_in[2];
    const float* Wv = (const float*)d_in[3];
    const float* bq = (const float*)d_in[4];
    const float* bk = (const float*)d_in[5];
    const float* bv = (const float*)d_in[6];
    const float* Wp = (const float*)d_in[7];
    const float* bp = (const float*)d_in[8];
    float* out = (float*)d_out;

    const size_t QKV_ELEMS = (size_t)2 * H_NUM * S_LEN * D_DIM;  // 4,194,304
    const size_t W_ELEMS   = (size_t)H_NUM * E_DIM * D_DIM;      // 1,048,576

    u16* q   = (u16*)d_ws;
    u16* k   = q   + QKV_ELEMS;
    u16* v   = k   + QKV_ELEMS;       // V^T [B,H,D,S], written directly by qkv_gemm
    u16* cc  = v   + QKV_ELEMS;
    u16* xb  = cc  + QKV_ELEMS;       // x bf16
    u16* wqt = xb  + QKV_ELEMS;       // [H][D][E] bf16  -- wqt||wkt||wvt = wcat [3072][1024]
    u16* wkt = wqt + W_ELEMS;
    u16* wvt = wkt + W_ELEMS;
    u16* wpt = wvt + W_ELEMS;         // [E][HD] bf16

    cvt_all<<<dim3(4096 + 768 + 256), 256, 0, stream>>>(
        x, xb, (int)QKV_ELEMS, Wq, Wk, Wv, wqt, wkt, wvt, Wp, wpt);

    qkv_gemm<<<dim3(32, 24), 128, 0, stream>>>(xb, wqt, bq, bk, bv, q, k, v);
    attn_fwd<<<dim3(512), 256, 0, stream>>>(q, k, v, cc);
    out_proj<<<dim3(512), 256, 0, stream>>>(cc, wpt, bp, out);
}